// Round 12
// baseline (1557.488 us; speedup 1.0000x reference)
//
#include <hip/hip_runtime.h>
#include <hip/hip_bf16.h>

#define BB 8
#define NN 4096
#define DD 64
#define SS 1024
#define KK 32
#define C1 64
#define C2 128

typedef unsigned int uint32;
typedef unsigned long long uint64;

constexpr int BSK = BB * SS * KK;   // 262144
constexpr int BS  = BB * SS;        // 8192

// ---- per-slot stats offsets (slot stride = 704 floats, 64 slots) ----
#define ST_S1_C1 0
#define ST_S2_C1 64
#define ST_S1_C2 128
#define ST_S2_C2 256
#define ST_S1_W0 384
#define ST_S2_W0 392
#define ST_S1_W1 400
#define ST_S2_W1 408
#define ST_S1_W2 416
#define ST_S2_W2 432
#define ST_S1_Y  448
#define ST_S2_Y  576
#define ST_STRIDE 704
#define N_SLOTS 64

#define PA_A_C1 0
#define PA_C_C1 64
#define PA_A_C2 128
#define PA_C_C2 256
#define PA_A_W0 384
#define PA_C_W0 392
#define PA_A_W1 400
#define PA_C_W1 408
#define PA_A_W2 416
#define PA_C_W2 432
#define PA_A_Y  448
#define PA_C_Y  576

// ------------------------------------------------------------------
// DPP cross-lane helpers.
// Packed-key trick (once-per-reduction only — per-element loops stay
// f32; f64 min/max is half-rate on CDNA4): key = (float_bits(d) << 32)
// | idx32 with d >= 0 finite. As an IEEE double the key is positive &
// finite, so fmax/fmin == u64 max/min.
// ------------------------------------------------------------------
#if __has_builtin(__builtin_amdgcn_update_dpp)
#define HAS_DPP 1
template <int CTRL>
__device__ __forceinline__ double dpp_f64(double x) {
    uint64 u = (uint64)__double_as_longlong(x);
    int lo = (int)(uint32)u, hi = (int)(uint32)(u >> 32);
    int lo2 = __builtin_amdgcn_update_dpp(lo, lo, CTRL, 0xf, 0xf, false);
    int hi2 = __builtin_amdgcn_update_dpp(hi, hi, CTRL, 0xf, 0xf, false);
    return __longlong_as_double((long long)(((uint64)(uint32)hi2 << 32) | (uint32)lo2));
}
__device__ __forceinline__ double wave_max_pack(double k) {
    k = fmax(k, dpp_f64<0x111>(k));   // row_shr:1
    k = fmax(k, dpp_f64<0x112>(k));   // row_shr:2
    k = fmax(k, dpp_f64<0x114>(k));   // row_shr:4
    k = fmax(k, dpp_f64<0x118>(k));   // row_shr:8
    k = fmax(k, dpp_f64<0x142>(k));   // row_bcast:15
    k = fmax(k, dpp_f64<0x143>(k));   // row_bcast:31
    return k;                          // lane 63 holds wave max
}
__device__ __forceinline__ double wave_min_pack(double k) {
    k = fmin(k, dpp_f64<0x111>(k));
    k = fmin(k, dpp_f64<0x112>(k));
    k = fmin(k, dpp_f64<0x114>(k));
    k = fmin(k, dpp_f64<0x118>(k));
    k = fmin(k, dpp_f64<0x142>(k));
    k = fmin(k, dpp_f64<0x143>(k));
    return k;                          // lane 63 holds wave min
}
__device__ __forceinline__ uint64 bcast63_u64(double k) {
#if __has_builtin(__builtin_amdgcn_readlane)
    uint64 u = (uint64)__double_as_longlong(k);
    int lo = __builtin_amdgcn_readlane((int)(uint32)u, 63);
    int hi = __builtin_amdgcn_readlane((int)(uint32)(u >> 32), 63);
    return ((uint64)(uint32)hi << 32) | (uint32)lo;
#else
    return (uint64)__double_as_longlong(__shfl(k, 63));
#endif
}
#define FPS_WRITER_LANE 63
template <int CTRL>
__device__ __forceinline__ float dpp_mov_f32(float x) {
    int r = __builtin_amdgcn_update_dpp(__float_as_int(x), __float_as_int(x),
                                        CTRL, 0xf, 0xf, false);
    return __int_as_float(r);
}
__device__ __forceinline__ float wave_sum_f32(float v) {
    v += dpp_mov_f32<0x111>(v);
    v += dpp_mov_f32<0x112>(v);
    v += dpp_mov_f32<0x114>(v);
    v += dpp_mov_f32<0x118>(v);
    v += dpp_mov_f32<0x142>(v);
    v += dpp_mov_f32<0x143>(v);
    return v;                          // lane 63 holds wave sum
}
#define LIN_WRITER 63
#else
#define HAS_DPP 0
__device__ __forceinline__ double wave_max_pack(double k) {
#pragma unroll
    for (int m = 32; m >= 1; m >>= 1) k = fmax(k, __shfl_xor(k, m));
    return k;
}
__device__ __forceinline__ double wave_min_pack(double k) {
#pragma unroll
    for (int m = 32; m >= 1; m >>= 1) k = fmin(k, __shfl_xor(k, m));
    return k;
}
__device__ __forceinline__ uint64 bcast63_u64(double k) {
    return (uint64)__double_as_longlong(k);   // already in all lanes
}
#define FPS_WRITER_LANE 0
__device__ __forceinline__ float wave_sum_f32(float v) {
#pragma unroll
    for (int m = 32; m >= 1; m >>= 1) v += __shfl_xor(v, m);
    return v;
}
#define LIN_WRITER 0
#endif

// ------------------------------------------------------------------
// fps_prep: blocks 0..7 run FPS (one per batch) while blocks 8..1055
// run the (FPS-independent) prep on otherwise-idle CUs:
//   blocks [8,520): transpose points [B,64,N]->[B,N,64] bf16 (one
//                   64x64 tile each, 512 threads)
//   blocks [520,1056): transpose conv weights + lin_w -> bf16
// FPS: 8 pts/thread in registers; per-point fmaxf accumulate + one
// descending equality scan for the index (fmaxf returns an input
// bit-exactly, so == is exact; smallest i == smallest n == jnp.argmax
// tie rule); packed-f64 DPP argmax once per step; one barrier/step;
// outputs via LDS hist + coalesced epilogue.
// ------------------------------------------------------------------
__global__ __launch_bounds__(512) void fps_prep(const float* __restrict__ xyz,
                                                float* __restrict__ new_xyz,
                                                float* __restrict__ out0,
                                                const float* __restrict__ points,
                                                __hip_bfloat16* __restrict__ ptsT,
                                                const float* __restrict__ c1_w,
                                                const float* __restrict__ c2_w,
                                                const float* __restrict__ lin_w,
                                                float* __restrict__ w1t,
                                                float* __restrict__ w2t,
                                                __hip_bfloat16* __restrict__ linB) {
    __shared__ __align__(16) float fsm[3 * NN];   // FPS: xs/ys/zs; prep: tile
    __shared__ int hist[SS];
    __shared__ __align__(16) double slots[2][8];
    int t = threadIdx.x;
    if (blockIdx.x >= 8) {
        int pb = blockIdx.x - 8;
        if (pb < 512) {
            // point transpose: tile aliases fsm (64*65 = 4160 floats)
            float* tile = fsm;
            int b = pb >> 6;
            int n0 = (pb & 63) * 64;
            for (int i = t; i < 4096; i += 512) {
                int d = i >> 6, n = i & 63;
                tile[d * 65 + n] = points[((size_t)b * DD + d) * NN + n0 + n];
            }
            __syncthreads();
            for (int i = t; i < 4096; i += 512) {
                int n = i >> 6, d = i & 63;
                ptsT[((size_t)b * NN + n0 + n) * DD + d] = __float2bfloat16(tile[d * 65 + n]);
            }
        } else {
            int i = (pb - 512) * 512 + t;   // [0, 274432)
            if (i < 4096) {
                int d = i >> 6, c = i & 63;
                w1t[d * 64 + c] = c1_w[c * 64 + d];
            }
            int j = i - 4096;
            if (j >= 0 && j < 8192) {
                int d = j >> 7, c = j & 127;
                w2t[d * 128 + c] = c2_w[c * 64 + d];
            }
            int l = i - 12288;
            if (l >= 0 && l < 262144) linB[l] = __float2bfloat16(lin_w[l]);
        }
        return;
    }
    // ---- FPS branch ----
    float* xs = fsm;
    float* ys = fsm + NN;
    float* zs = fsm + 2 * NN;
    int b = blockIdx.x;
    int wv = t >> 6, lane = t & 63;
    const float* base = xyz + (size_t)b * 3 * NN;
    float px[8], py[8], pz[8], dl[8];
    uint32 lidx[8];
#pragma unroll
    for (int i = 0; i < 8; i++) {
        int n = t + 512 * i;
        px[i] = base[n];
        py[i] = base[NN + n];
        pz[i] = base[2 * NN + n];
        xs[n] = px[i];
        ys[n] = py[i];
        zs[n] = pz[i];
        dl[i] = 1e10f;
        lidx[i] = (uint32)(NN - 1 - n);
    }
    if (t == 0) hist[0] = 0;
    __syncthreads();
    int far = 0;
    for (int step = 1; step < SS; step++) {
        int p = step & 1;
        float cx = xs[far], cy = ys[far], cz = zs[far];
        float bmax = -1.0f;
#pragma unroll
        for (int i = 0; i < 8; i++) {
            float dx = __fsub_rn(px[i], cx);
            float dy = __fsub_rn(py[i], cy);
            float dz = __fsub_rn(pz[i], cz);
            float d = __fadd_rn(__fadd_rn(__fmul_rn(dx, dx), __fmul_rn(dy, dy)),
                                __fmul_rn(dz, dz));
            float nd = fminf(dl[i], d);
            dl[i] = nd;
            bmax = fmaxf(bmax, nd);
        }
        // recover first matching index (descending overwrite -> smallest i)
        uint32 bl = lidx[7];
#pragma unroll
        for (int i = 6; i >= 0; i--) bl = (dl[i] == bmax) ? lidx[i] : bl;
        uint64 kbits = ((uint64)__float_as_uint(bmax) << 32) | bl;
        double kbest = wave_max_pack(__longlong_as_double((long long)kbits));
        if (lane == FPS_WRITER_LANE) slots[p][wv] = kbest;
        __syncthreads();
        double s0 = slots[p][0], s1 = slots[p][1];
        double s2 = slots[p][2], s3 = slots[p][3];
        double s4 = slots[p][4], s5 = slots[p][5];
        double s6 = slots[p][6], s7 = slots[p][7];
        double m0 = fmax(s0, s1), m1 = fmax(s2, s3);
        double m2 = fmax(s4, s5), m3 = fmax(s6, s7);
        double bk = fmax(fmax(m0, m1), fmax(m2, m3));
        uint64 kb = (uint64)__double_as_longlong(bk);
        int bbx = (NN - 1) - (int)(uint32)(kb & 0xffffffffull);
        far = bbx;
        if (t == 0) hist[step] = bbx;
    }
    __syncthreads();
    // epilogue: coalesced output writes
    for (int s = t; s < SS; s += 512) {
        int idx = hist[s];
        float x = xs[idx], y = ys[idx], z = zs[idx];
        size_t q = (size_t)(b * SS + s);
        new_xyz[q * 3 + 0] = x;
        new_xyz[q * 3 + 1] = y;
        new_xyz[q * 3 + 2] = z;
        out0[(size_t)b * 3 * SS + 0 * SS + s] = x;
        out0[(size_t)b * 3 * SS + 1 * SS + s] = y;
        out0[(size_t)b * 3 * SS + 2 * SS + s] = z;
    }
}

// ------------------------------------------------------------------
// kNN: one wave per query; dists in registers, 64-bit exclusion mask.
// Inner scan is f32 compare/select (full-rate); only the cross-lane
// reduce uses the packed-f64 DPP min.
// ------------------------------------------------------------------
__global__ __launch_bounds__(256) void knn_wave(const float* __restrict__ xyz,
                                                const float* __restrict__ new_xyz,
                                                int* __restrict__ nidx,
                                                float* __restrict__ offs) {
    int wv = threadIdx.x >> 6, lane = threadIdx.x & 63;
    int q = blockIdx.x * 4 + wv;         // 0..8191
    int b = q >> 10;
    const float* base = xyz + (size_t)b * 3 * NN;
    float sx = new_xyz[(size_t)q * 3 + 0];
    float sy = new_xyz[(size_t)q * 3 + 1];
    float sz = new_xyz[(size_t)q * 3 + 2];
    float s2 = __fadd_rn(__fadd_rn(__fmul_rn(sx, sx), __fmul_rn(sy, sy)), __fmul_rn(sz, sz));
    float dl[64];
#pragma unroll
    for (int i = 0; i < 64; i++) {
        int n = i * 64 + lane;
        float x = base[n], y = base[NN + n], z = base[2 * NN + n];
        float d2 = __fadd_rn(__fadd_rn(__fmul_rn(x, x), __fmul_rn(y, y)), __fmul_rn(z, z));
        float dot = __fadd_rn(__fadd_rn(__fmul_rn(sx, x), __fmul_rn(sy, y)), __fmul_rn(sz, z));
        float v = __fmul_rn(-2.0f, dot);
        v = __fadd_rn(v, s2);
        v = __fadd_rn(v, d2);
        dl[i] = v;
    }
    const float MASKF = __uint_as_float(0x7F7FFFFFu);   // FLT_MAX
    unsigned long long excl = 0ull;
    for (int k = 0; k < KK; k++) {
        float best = MASKF;
        int bslot = 0;
#pragma unroll
        for (int i = 0; i < 64; i++) {
            bool ok = ((excl >> i) & 1ull) == 0ull;
            float v = ok ? dl[i] : MASKF;
            if (v < best) { best = v; bslot = i; }   // strict <: lowest slot kept
        }
        uint64 kbits = ((uint64)__float_as_uint(best) << 32) |
                       (uint32)(bslot * 64 + lane);
        double kb = wave_min_pack(__longlong_as_double((long long)kbits));
        uint64 r = bcast63_u64(kb);
        int bi = (int)(uint32)(r & 0xffffffffull);
        if ((bi & 63) == lane) excl |= (1ull << (bi >> 6));
        if (lane == 0) {
            nidx[(size_t)q * KK + k] = bi;
            size_t oo = ((size_t)q * KK + k) * 3;
            offs[oo + 0] = __fsub_rn(base[bi], sx);
            offs[oo + 1] = __fsub_rn(base[NN + bi], sy);
            offs[oo + 2] = __fsub_rn(base[2 * NN + bi], sz);
        }
    }
}

// ------------------------------------------------------------------
// staging: gather 32 neighbors x 64 dims (bf16 -> fp32 LDS), uint4 loads
// ------------------------------------------------------------------
__device__ __forceinline__ void stage_pts(const __hip_bfloat16* __restrict__ ptsT,
                                          const int* __restrict__ nidx,
                                          int q, int b, int t, float* pts) {
    int k = t >> 3, d8 = t & 7;
    int nn = nidx[(size_t)q * KK + k];
    uint4 u = ((const uint4*)ptsT)[((size_t)b * NN + nn) * 8 + d8];
    float4 lo, hi;
    lo.x = __uint_as_float(u.x << 16); lo.y = __uint_as_float(u.x & 0xffff0000u);
    lo.z = __uint_as_float(u.y << 16); lo.w = __uint_as_float(u.y & 0xffff0000u);
    hi.x = __uint_as_float(u.z << 16); hi.y = __uint_as_float(u.z & 0xffff0000u);
    hi.z = __uint_as_float(u.w << 16); hi.w = __uint_as_float(u.w & 0xffff0000u);
    *(float4*)&pts[k * 64 + d8 * 8] = lo;
    *(float4*)&pts[k * 64 + d8 * 8 + 4] = hi;
}

// ------------------------------------------------------------------
// pass A: conv1 stats + w0 stats (float4 LDS reads, slotted atomics)
// ------------------------------------------------------------------
__global__ __launch_bounds__(256) void pass_a(const __hip_bfloat16* __restrict__ ptsT,
                                              const int* __restrict__ nidx,
                                              const float* __restrict__ offs,
                                              const float* __restrict__ w1t,
                                              const float* __restrict__ c1_b,
                                              const float* __restrict__ w0_w,
                                              const float* __restrict__ w0_b,
                                              float* __restrict__ stats) {
    __shared__ __align__(16) float pts[2048];
    __shared__ float red1[256], red2[256];
    int blk = blockIdx.x, t = threadIdx.x;
    int b = blk >> 10;
    int slot = blk & (N_SLOTS - 1);
    stage_pts(ptsT, nidx, blk, b, t, pts);
    __syncthreads();
    int c = t & 63, kg = t >> 6;
    float bias = c1_b[c];
    float acc[8];
#pragma unroll
    for (int j = 0; j < 8; j++) acc[j] = bias;
    for (int d4 = 0; d4 < 16; d4++) {
        float w0 = w1t[(4 * d4 + 0) * 64 + c];
        float w1v = w1t[(4 * d4 + 1) * 64 + c];
        float w2v = w1t[(4 * d4 + 2) * 64 + c];
        float w3 = w1t[(4 * d4 + 3) * 64 + c];
#pragma unroll
        for (int j = 0; j < 8; j++) {
            const float4 p = *(const float4*)&pts[(kg + 4 * j) * 64 + 4 * d4];
            acc[j] = fmaf(p.x, w0, acc[j]);
            acc[j] = fmaf(p.y, w1v, acc[j]);
            acc[j] = fmaf(p.z, w2v, acc[j]);
            acc[j] = fmaf(p.w, w3, acc[j]);
        }
    }
    float s1 = 0.f, s2 = 0.f;
#pragma unroll
    for (int j = 0; j < 8; j++) { s1 += acc[j]; s2 += acc[j] * acc[j]; }
    red1[t] = s1;
    red2[t] = s2;
    __syncthreads();
    if (t < 64) {
        atomicAdd(&stats[slot * ST_STRIDE + ST_S1_C1 + t],
                  red1[t] + red1[t + 64] + red1[t + 128] + red1[t + 192]);
        atomicAdd(&stats[slot * ST_STRIDE + ST_S2_C1 + t],
                  red2[t] + red2[t + 64] + red2[t + 128] + red2[t + 192]);
    }
    // w0 stats
    int k0 = t >> 3, c0 = t & 7;
    size_t oo = ((size_t)blk * KK + k0) * 3;
    float h = w0_b[c0];
    h = fmaf(offs[oo + 0], w0_w[c0 * 3 + 0], h);
    h = fmaf(offs[oo + 1], w0_w[c0 * 3 + 1], h);
    h = fmaf(offs[oo + 2], w0_w[c0 * 3 + 2], h);
    __syncthreads();
    red1[t] = h;
    red2[t] = h * h;
    __syncthreads();
    if (t < 8) {
        float a = 0.f, q = 0.f;
        for (int j = t; j < 256; j += 8) { a += red1[j]; q += red2[j]; }
        atomicAdd(&stats[slot * ST_STRIDE + ST_S1_W0 + t], a);
        atomicAdd(&stats[slot * ST_STRIDE + ST_S2_W0 + t], q);
    }
}

// ------------------------------------------------------------------
// finalize BN(s) from slotted stats
// ------------------------------------------------------------------
__device__ __forceinline__ void fin_one(const float* stats, float* params,
                                        const float* g, const float* be,
                                        int s1o, int s2o, int ao, int co,
                                        int nch, float inv, int t) {
    if (t < nch) {
        float s1 = 0.f, s2 = 0.f;
        for (int s = 0; s < N_SLOTS; s++) {
            s1 += stats[s * ST_STRIDE + s1o + t];
            s2 += stats[s * ST_STRIDE + s2o + t];
        }
        float m = s1 * inv;
        float v = s2 * inv - m * m;
        float a = g[t] * rsqrtf(v + 1e-5f);
        params[ao + t] = a;
        params[co + t] = be[t] - m * a;
    }
}

__global__ void finalize_bn(const float* __restrict__ stats, float* __restrict__ params,
                            const float* __restrict__ g, const float* __restrict__ be,
                            int s1o, int s2o, int ao, int co, int nch, float inv) {
    fin_one(stats, params, g, be, s1o, s2o, ao, co, nch, inv, threadIdx.x);
}

__global__ void finalize_two(const float* __restrict__ stats, float* __restrict__ params,
                             const float* __restrict__ gA, const float* __restrict__ beA,
                             int s1A, int s2A, int aA, int cA, int nA, float invA,
                             const float* __restrict__ gB, const float* __restrict__ beB,
                             int s1B, int s2B, int aB, int cB, int nB, float invB) {
    if (blockIdx.x == 0)
        fin_one(stats, params, gA, beA, s1A, s2A, aA, cA, nA, invA, threadIdx.x);
    else
        fin_one(stats, params, gB, beB, s1B, s2B, aB, cB, nB, invB, threadIdx.x);
}

// ------------------------------------------------------------------
// pass B: conv1 recompute + bn1relu -> f1; conv2 stats; w1 stats
// ------------------------------------------------------------------
__global__ __launch_bounds__(256) void pass_b(const __hip_bfloat16* __restrict__ ptsT,
                                              const int* __restrict__ nidx,
                                              const float* __restrict__ offs,
                                              const float* __restrict__ w1t,
                                              const float* __restrict__ c1_b,
                                              const float* __restrict__ w2t,
                                              const float* __restrict__ c2_b,
                                              const float* __restrict__ w0_w,
                                              const float* __restrict__ w0_b,
                                              const float* __restrict__ w1_w,
                                              const float* __restrict__ w1_b,
                                              const float* __restrict__ params,
                                              float* __restrict__ stats) {
    __shared__ __align__(16) float pts[2048];
    __shared__ __align__(16) float f1[2048];
    __shared__ float red1[256], red2[256];
    int blk = blockIdx.x, t = threadIdx.x;
    int b = blk >> 10;
    int slot = blk & (N_SLOTS - 1);
    stage_pts(ptsT, nidx, blk, b, t, pts);
    __syncthreads();
    // conv1 + bn1 + relu
    {
        int c = t & 63, kg = t >> 6;
        float a1 = params[PA_A_C1 + c], cc1 = params[PA_C_C1 + c], bias = c1_b[c];
        float acc[8];
#pragma unroll
        for (int j = 0; j < 8; j++) acc[j] = bias;
        for (int d4 = 0; d4 < 16; d4++) {
            float w0 = w1t[(4 * d4 + 0) * 64 + c];
            float w1v = w1t[(4 * d4 + 1) * 64 + c];
            float w2v = w1t[(4 * d4 + 2) * 64 + c];
            float w3 = w1t[(4 * d4 + 3) * 64 + c];
#pragma unroll
            for (int j = 0; j < 8; j++) {
                const float4 p = *(const float4*)&pts[(kg + 4 * j) * 64 + 4 * d4];
                acc[j] = fmaf(p.x, w0, acc[j]);
                acc[j] = fmaf(p.y, w1v, acc[j]);
                acc[j] = fmaf(p.z, w2v, acc[j]);
                acc[j] = fmaf(p.w, w3, acc[j]);
            }
        }
#pragma unroll
        for (int j = 0; j < 8; j++)
            f1[(kg + 4 * j) * 64 + c] = fmaxf(fmaf(acc[j], a1, cc1), 0.f);
    }
    __syncthreads();
    // conv2 stats
    {
        int c = t & 127, kg = t >> 7;
        float bias = c2_b[c];
        float acc[16];
#pragma unroll
        for (int j = 0; j < 16; j++) acc[j] = bias;
        for (int d4 = 0; d4 < 16; d4++) {
            float w0 = w2t[(4 * d4 + 0) * 128 + c];
            float w1v = w2t[(4 * d4 + 1) * 128 + c];
            float w2v = w2t[(4 * d4 + 2) * 128 + c];
            float w3 = w2t[(4 * d4 + 3) * 128 + c];
#pragma unroll
            for (int j = 0; j < 16; j++) {
                const float4 p = *(const float4*)&f1[(kg + 2 * j) * 64 + 4 * d4];
                acc[j] = fmaf(p.x, w0, acc[j]);
                acc[j] = fmaf(p.y, w1v, acc[j]);
                acc[j] = fmaf(p.z, w2v, acc[j]);
                acc[j] = fmaf(p.w, w3, acc[j]);
            }
        }
        float s1 = 0.f, s2 = 0.f;
#pragma unroll
        for (int j = 0; j < 16; j++) { s1 += acc[j]; s2 += acc[j] * acc[j]; }
        red1[t] = s1;
        red2[t] = s2;
    }
    __syncthreads();
    if (t < 128) {
        atomicAdd(&stats[slot * ST_STRIDE + ST_S1_C2 + t], red1[t] + red1[t + 128]);
        atomicAdd(&stats[slot * ST_STRIDE + ST_S2_C2 + t], red2[t] + red2[t + 128]);
    }
    // w1 stats
    {
        int k0 = t >> 3, c0 = t & 7;
        size_t oo = ((size_t)blk * KK + k0) * 3;
        float o0 = offs[oo], o1 = offs[oo + 1], o2 = offs[oo + 2];
        float h0[8];
#pragma unroll
        for (int j = 0; j < 8; j++) {
            float hh = w0_b[j];
            hh = fmaf(o0, w0_w[j * 3 + 0], hh);
            hh = fmaf(o1, w0_w[j * 3 + 1], hh);
            hh = fmaf(o2, w0_w[j * 3 + 2], hh);
            h0[j] = fmaxf(fmaf(hh, params[PA_A_W0 + j], params[PA_C_W0 + j]), 0.f);
        }
        float h = w1_b[c0];
#pragma unroll
        for (int j = 0; j < 8; j++) h = fmaf(h0[j], w1_w[c0 * 8 + j], h);
        __syncthreads();
        red1[t] = h;
        red2[t] = h * h;
        __syncthreads();
        if (t < 8) {
            float a = 0.f, q = 0.f;
            for (int j = t; j < 256; j += 8) { a += red1[j]; q += red2[j]; }
            atomicAdd(&stats[slot * ST_STRIDE + ST_S1_W1 + t], a);
            atomicAdd(&stats[slot * ST_STRIDE + ST_S2_W1 + t], q);
        }
    }
}

// ------------------------------------------------------------------
// w2 stats: full weightnet chain per point
// ------------------------------------------------------------------
__global__ __launch_bounds__(256) void pass_w2(const float* __restrict__ offs,
                                               const float* __restrict__ w0_w,
                                               const float* __restrict__ w0_b,
                                               const float* __restrict__ w1_w,
                                               const float* __restrict__ w1_b,
                                               const float* __restrict__ w2_w,
                                               const float* __restrict__ w2_b,
                                               const float* __restrict__ params,
                                               float* __restrict__ stats) {
    int i = blockIdx.x * 256 + threadIdx.x;
    int slot = blockIdx.x & (N_SLOTS - 1);
    size_t oo = (size_t)i * 3;
    float o0 = offs[oo], o1 = offs[oo + 1], o2 = offs[oo + 2];
    float h0[8], h1[8];
#pragma unroll
    for (int j = 0; j < 8; j++) {
        float hh = w0_b[j];
        hh = fmaf(o0, w0_w[j * 3 + 0], hh);
        hh = fmaf(o1, w0_w[j * 3 + 1], hh);
        hh = fmaf(o2, w0_w[j * 3 + 2], hh);
        h0[j] = fmaxf(fmaf(hh, params[PA_A_W0 + j], params[PA_C_W0 + j]), 0.f);
    }
#pragma unroll
    for (int j = 0; j < 8; j++) {
        float hh = w1_b[j];
#pragma unroll
        for (int q = 0; q < 8; q++) hh = fmaf(h0[q], w1_w[j * 8 + q], hh);
        h1[j] = fmaxf(fmaf(hh, params[PA_A_W1 + j], params[PA_C_W1 + j]), 0.f);
    }
#pragma unroll
    for (int c = 0; c < 16; c++) {
        float h = w2_b[c];
#pragma unroll
        for (int q = 0; q < 8; q++) h = fmaf(h1[q], w2_w[c * 8 + q], h);
        float v = wave_sum_f32(h);
        float s = wave_sum_f32(h * h);
        if ((threadIdx.x & 63) == LIN_WRITER) {
            atomicAdd(&stats[slot * ST_STRIDE + ST_S1_W2 + c], v);
            atomicAdd(&stats[slot * ST_STRIDE + ST_S2_W2 + c], s);
        }
    }
}

// ------------------------------------------------------------------
// fused tail (NQ=1, R8 structure — best measured):
// conv1->conv2->weightnet->einsum->linear + y stats
// ------------------------------------------------------------------
__global__ __launch_bounds__(256) void fused_tail(
        const __hip_bfloat16* __restrict__ ptsT, const int* __restrict__ nidx,
        const float* __restrict__ offs,
        const float* __restrict__ w1t, const float* __restrict__ c1_b,
        const float* __restrict__ w2t, const float* __restrict__ c2_b,
        const float* __restrict__ w0_w, const float* __restrict__ w0_b,
        const float* __restrict__ w1_w, const float* __restrict__ w1_b,
        const float* __restrict__ w2_w, const float* __restrict__ w2_b,
        const __hip_bfloat16* __restrict__ linB, const float* __restrict__ lin_b,
        const float* __restrict__ params, float* __restrict__ stats,
        float* __restrict__ ypre) {
    __shared__ __align__(16) float sm[8704];
    float* pts   = sm;            // [0,2048)  later reused as feats
    float* f1    = sm + 2048;     // [2048,4096)
    float* f2    = sm + 4096;     // [4096,8192)
    float* wg    = sm + 8192;     // [8192,8704)
    int blk = blockIdx.x, t = threadIdx.x;
    int b = blk >> 10;
    int slot = blk & (N_SLOTS - 1);
    stage_pts(ptsT, nidx, blk, b, t, pts);
    // weightnet -> wg (independent of pts)
    for (int idx = t; idx < KK * 16; idx += 256) {
        int k = idx >> 4, cw = idx & 15;
        size_t oo = ((size_t)blk * KK + k) * 3;
        float o0 = offs[oo], o1 = offs[oo + 1], o2 = offs[oo + 2];
        float h0[8], h1[8];
#pragma unroll
        for (int j = 0; j < 8; j++) {
            float hh = w0_b[j];
            hh = fmaf(o0, w0_w[j * 3 + 0], hh);
            hh = fmaf(o1, w0_w[j * 3 + 1], hh);
            hh = fmaf(o2, w0_w[j * 3 + 2], hh);
            h0[j] = fmaxf(fmaf(hh, params[PA_A_W0 + j], params[PA_C_W0 + j]), 0.f);
        }
#pragma unroll
        for (int j = 0; j < 8; j++) {
            float hh = w1_b[j];
#pragma unroll
            for (int q = 0; q < 8; q++) hh = fmaf(h0[q], w1_w[j * 8 + q], hh);
            h1[j] = fmaxf(fmaf(hh, params[PA_A_W1 + j], params[PA_C_W1 + j]), 0.f);
        }
        float h = w2_b[cw];
#pragma unroll
        for (int q = 0; q < 8; q++) h = fmaf(h1[q], w2_w[cw * 8 + q], h);
        wg[idx] = fmaxf(fmaf(h, params[PA_A_W2 + cw], params[PA_C_W2 + cw]), 0.f);
    }
    __syncthreads();
    // conv1 + bn1 relu -> f1
    {
        int c = t & 63, kg = t >> 6;
        float a1 = params[PA_A_C1 + c], cc1 = params[PA_C_C1 + c], bias = c1_b[c];
        float acc[8];
#pragma unroll
        for (int j = 0; j < 8; j++) acc[j] = bias;
        for (int d4 = 0; d4 < 16; d4++) {
            float w0 = w1t[(4 * d4 + 0) * 64 + c];
            float w1v = w1t[(4 * d4 + 1) * 64 + c];
            float w2v = w1t[(4 * d4 + 2) * 64 + c];
            float w3 = w1t[(4 * d4 + 3) * 64 + c];
#pragma unroll
            for (int j = 0; j < 8; j++) {
                const float4 p = *(const float4*)&pts[(kg + 4 * j) * 64 + 4 * d4];
                acc[j] = fmaf(p.x, w0, acc[j]);
                acc[j] = fmaf(p.y, w1v, acc[j]);
                acc[j] = fmaf(p.z, w2v, acc[j]);
                acc[j] = fmaf(p.w, w3, acc[j]);
            }
        }
#pragma unroll
        for (int j = 0; j < 8; j++)
            f1[(kg + 4 * j) * 64 + c] = fmaxf(fmaf(acc[j], a1, cc1), 0.f);
    }
    __syncthreads();
    // conv2 + bn2 relu -> f2
    {
        int c = t & 127, kg = t >> 7;
        float a2 = params[PA_A_C2 + c], cc2 = params[PA_C_C2 + c], bias = c2_b[c];
        float acc[16];
#pragma unroll
        for (int j = 0; j < 16; j++) acc[j] = bias;
        for (int d4 = 0; d4 < 16; d4++) {
            float w0 = w2t[(4 * d4 + 0) * 128 + c];
            float w1v = w2t[(4 * d4 + 1) * 128 + c];
            float w2v = w2t[(4 * d4 + 2) * 128 + c];
            float w3 = w2t[(4 * d4 + 3) * 128 + c];
#pragma unroll
            for (int j = 0; j < 16; j++) {
                const float4 p = *(const float4*)&f1[(kg + 2 * j) * 64 + 4 * d4];
                acc[j] = fmaf(p.x, w0, acc[j]);
                acc[j] = fmaf(p.y, w1v, acc[j]);
                acc[j] = fmaf(p.z, w2v, acc[j]);
                acc[j] = fmaf(p.w, w3, acc[j]);
            }
        }
#pragma unroll
        for (int j = 0; j < 16; j++)
            f2[(kg + 2 * j) * 128 + c] = fmaxf(fmaf(acc[j], a2, cc2), 0.f);
    }
    __syncthreads();
    // einsum -> feats (aliases pts): thread owns cc = t&127, w-half = t>>7
    {
        int cc = t & 127, wh = t >> 7;
        float acc[8];
#pragma unroll
        for (int i = 0; i < 8; i++) acc[i] = 0.f;
        for (int k = 0; k < KK; k++) {
            float fv = f2[k * 128 + cc];
            const float4 wa = *(const float4*)&wg[k * 16 + 8 * wh];
            const float4 wb = *(const float4*)&wg[k * 16 + 8 * wh + 4];
            acc[0] = fmaf(fv, wa.x, acc[0]);
            acc[1] = fmaf(fv, wa.y, acc[1]);
            acc[2] = fmaf(fv, wa.z, acc[2]);
            acc[3] = fmaf(fv, wa.w, acc[3]);
            acc[4] = fmaf(fv, wb.x, acc[4]);
            acc[5] = fmaf(fv, wb.y, acc[5]);
            acc[6] = fmaf(fv, wb.z, acc[6]);
            acc[7] = fmaf(fv, wb.w, acc[7]);
        }
        *(float4*)&pts[cc * 16 + 8 * wh]     = *(float4*)&acc[0];
        *(float4*)&pts[cc * 16 + 8 * wh + 4] = *(float4*)&acc[4];
    }
    __syncthreads();
    float* feats = pts;
    // linear 2048 -> 128: feats hoisted to registers, DPP wave-sum
    {
        int wv = t >> 6, lane = t & 63;
        float4 fv[8];
#pragma unroll
        for (int j0 = 0; j0 < 8; j0++)
            fv[j0] = *(const float4*)&feats[(j0 * 64 + lane) * 4];
        for (int oi = 0; oi < 32; oi++) {
            int o = wv * 32 + oi;
            const uint2* lw = (const uint2*)(linB + (size_t)o * 2048);
            float acc = 0.f;
#pragma unroll
            for (int j0 = 0; j0 < 8; j0++) {
                uint2 u = lw[j0 * 64 + lane];
                acc = fmaf(fv[j0].x, __uint_as_float(u.x << 16), acc);
                acc = fmaf(fv[j0].y, __uint_as_float(u.x & 0xffff0000u), acc);
                acc = fmaf(fv[j0].z, __uint_as_float(u.y << 16), acc);
                acc = fmaf(fv[j0].w, __uint_as_float(u.y & 0xffff0000u), acc);
            }
            acc = wave_sum_f32(acc);
            if (lane == LIN_WRITER) {
                float y = acc + lin_b[o];
                ypre[(size_t)blk * 128 + o] = y;
                atomicAdd(&stats[slot * ST_STRIDE + ST_S1_Y + o], y);
                atomicAdd(&stats[slot * ST_STRIDE + ST_S2_Y + o], y * y);
            }
        }
    }
}

// ------------------------------------------------------------------
// final BN + relu + tiled transpose write to out1 [B,128,S]
// ------------------------------------------------------------------
__global__ __launch_bounds__(256) void bn_y(const float* __restrict__ ypre,
                                            const float* __restrict__ params,
                                            float* __restrict__ out1) {
    __shared__ float tile[64 * 133];
    int blk = blockIdx.x;
    int b = blk >> 4;
    int s0 = (blk & 15) * 64;
    int t = threadIdx.x;
#pragma unroll
    for (int i = 0; i < 32; i++) {
        int idx = i * 256 + t;
        int s = idx >> 7, c = idx & 127;
        tile[s * 133 + c] = ypre[(((size_t)b << 10) + s0 + s) * 128 + c];
    }
    __syncthreads();
#pragma unroll
    for (int i = 0; i < 32; i++) {
        int idx = i * 256 + t;
        int c = idx >> 6, s = idx & 63;
        float v = tile[s * 133 + c];
        out1[((size_t)b * 128 + c) * 1024 + s0 + s] =
            fmaxf(fmaf(v, params[PA_A_Y + c], params[PA_C_Y + c]), 0.f);
    }
}

// ------------------------------------------------------------------
extern "C" void kernel_launch(void* const* d_in, const int* in_sizes, int n_in,
                              void* d_out, int out_size, void* d_ws, size_t ws_size,
                              hipStream_t stream) {
    const float* xyz    = (const float*)d_in[0];
    const float* points = (const float*)d_in[1];
    const float* c1_w = (const float*)d_in[2];
    const float* c1_b = (const float*)d_in[3];
    const float* g1   = (const float*)d_in[4];
    const float* b1   = (const float*)d_in[5];
    const float* c2_w = (const float*)d_in[6];
    const float* c2_b = (const float*)d_in[7];
    const float* g2   = (const float*)d_in[8];
    const float* b2   = (const float*)d_in[9];
    const float* w0_w = (const float*)d_in[10];
    const float* w0_b = (const float*)d_in[11];
    const float* w0_g = (const float*)d_in[12];
    const float* w0_be= (const float*)d_in[13];
    const float* w1_w = (const float*)d_in[14];
    const float* w1_b = (const float*)d_in[15];
    const float* w1_g = (const float*)d_in[16];
    const float* w1_be= (const float*)d_in[17];
    const float* w2_w = (const float*)d_in[18];
    const float* w2_b = (const float*)d_in[19];
    const float* w2_g = (const float*)d_in[20];
    const float* w2_be= (const float*)d_in[21];
    const float* lin_w= (const float*)d_in[22];
    const float* lin_b= (const float*)d_in[23];
    const float* lg   = (const float*)d_in[24];
    const float* lb   = (const float*)d_in[25];

    float* out0 = (float*)d_out;
    float* out1 = out0 + (size_t)BB * 3 * SS;

    char* wsb = (char*)d_ws;
    int*   nidx    = (int*)(wsb + 0);                         // 1,048,576
    float* offs    = (float*)(wsb + 1048576);                 // 3,145,728
    float* new_xyz = (float*)(wsb + 4194304);                 // 98,304
    float* ypre    = (float*)(wsb + 4292608);                 // 4,194,304
    __hip_bfloat16* ptsT = (__hip_bfloat16*)(wsb + 8486912);  // 4,194,304
    float* w1t     = (float*)(wsb + 12681216);                // 16,384
    float* w2t     = (float*)(wsb + 12697600);                // 32,768
    __hip_bfloat16* linB = (__hip_bfloat16*)(wsb + 12730368); // 524,288
    float* stats   = (float*)(wsb + 13254656);                // 180,224
    float* params  = (float*)(wsb + 13434880);                // 2,816

    hipMemsetAsync(stats, 0, N_SLOTS * ST_STRIDE * sizeof(float), stream);

    fps_prep<<<1056, 512, 0, stream>>>(xyz, new_xyz, out0,
                                       points, ptsT, c1_w, c2_w, lin_w,
                                       w1t, w2t, linB);
    knn_wave<<<BS / 4, 256, 0, stream>>>(xyz, new_xyz, nidx, offs);

    pass_a<<<BS, 256, 0, stream>>>(ptsT, nidx, offs, w1t, c1_b, w0_w, w0_b, stats);
    finalize_two<<<2, 128, 0, stream>>>(stats, params,
                                        g1, b1, ST_S1_C1, ST_S2_C1, PA_A_C1, PA_C_C1, 64, 1.f / BSK,
                                        w0_g, w0_be, ST_S1_W0, ST_S2_W0, PA_A_W0, PA_C_W0, 8, 1.f / BSK);

    pass_b<<<BS, 256, 0, stream>>>(ptsT, nidx, offs, w1t, c1_b, w2t, c2_b,
                                   w0_w, w0_b, w1_w, w1_b, params, stats);
    finalize_two<<<2, 128, 0, stream>>>(stats, params,
                                        g2, b2, ST_S1_C2, ST_S2_C2, PA_A_C2, PA_C_C2, 128, 1.f / BSK,
                                        w1_g, w1_be, ST_S1_W1, ST_S2_W1, PA_A_W1, PA_C_W1, 8, 1.f / BSK);

    pass_w2<<<BSK / 256, 256, 0, stream>>>(offs, w0_w, w0_b, w1_w, w1_b, w2_w, w2_b,
                                           params, stats);
    finalize_bn<<<1, 128, 0, stream>>>(stats, params, w2_g, w2_be,
                                       ST_S1_W2, ST_S2_W2, PA_A_W2, PA_C_W2, 16, 1.f / BSK);

    fused_tail<<<BS, 256, 0, stream>>>(ptsT, nidx, offs, w1t, c1_b, w2t, c2_b,
                                       w0_w, w0_b, w1_w, w1_b, w2_w, w2_b,
                                       linB, lin_b, params, stats, ypre);
    finalize_bn<<<1, 128, 0, stream>>>(stats, params, lg, lb,
                                       ST_S1_Y, ST_S2_Y, PA_A_Y, PA_C_Y, 128, 1.f / BS);

    bn_y<<<BB * 16, 256, 0, stream>>>(ypre, params, out1);
}

// Round 13
// 1544.490 us; speedup vs baseline: 1.0084x; 1.0084x over previous
//
#include <hip/hip_runtime.h>
#include <hip/hip_bf16.h>

#define BB 8
#define NN 4096
#define DD 64
#define SS 1024
#define KK 32
#define C1 64
#define C2 128

typedef unsigned int uint32;
typedef unsigned long long uint64;

constexpr int BSK = BB * SS * KK;   // 262144
constexpr int BS  = BB * SS;        // 8192

// ---- per-slot stats offsets (slot stride = 704 floats, 64 slots) ----
#define ST_S1_C1 0
#define ST_S2_C1 64
#define ST_S1_C2 128
#define ST_S2_C2 256
#define ST_S1_W0 384
#define ST_S2_W0 392
#define ST_S1_W1 400
#define ST_S2_W1 408
#define ST_S1_W2 416
#define ST_S2_W2 432
#define ST_S1_Y  448
#define ST_S2_Y  576
#define ST_STRIDE 704
#define N_SLOTS 64

#define PA_A_C1 0
#define PA_C_C1 64
#define PA_A_C2 128
#define PA_C_C2 256
#define PA_A_W0 384
#define PA_C_W0 392
#define PA_A_W1 400
#define PA_C_W1 408
#define PA_A_W2 416
#define PA_C_W2 432
#define PA_A_Y  448
#define PA_C_Y  576

// ------------------------------------------------------------------
// DPP cross-lane helpers.
// Packed-key trick (once-per-reduction only — per-element loops stay
// f32; f64 min/max is half-rate on CDNA4): key = (float_bits(d) << 32)
// | idx32 with d >= 0 finite. As an IEEE double the key is positive &
// finite, so fmax/fmin == u64 max/min.
// ------------------------------------------------------------------
#if __has_builtin(__builtin_amdgcn_update_dpp)
#define HAS_DPP 1
template <int CTRL>
__device__ __forceinline__ double dpp_f64(double x) {
    uint64 u = (uint64)__double_as_longlong(x);
    int lo = (int)(uint32)u, hi = (int)(uint32)(u >> 32);
    int lo2 = __builtin_amdgcn_update_dpp(lo, lo, CTRL, 0xf, 0xf, false);
    int hi2 = __builtin_amdgcn_update_dpp(hi, hi, CTRL, 0xf, 0xf, false);
    return __longlong_as_double((long long)(((uint64)(uint32)hi2 << 32) | (uint32)lo2));
}
__device__ __forceinline__ double wave_max_pack(double k) {
    k = fmax(k, dpp_f64<0x111>(k));   // row_shr:1
    k = fmax(k, dpp_f64<0x112>(k));   // row_shr:2
    k = fmax(k, dpp_f64<0x114>(k));   // row_shr:4
    k = fmax(k, dpp_f64<0x118>(k));   // row_shr:8
    k = fmax(k, dpp_f64<0x142>(k));   // row_bcast:15
    k = fmax(k, dpp_f64<0x143>(k));   // row_bcast:31
    return k;                          // lane 63 holds wave max
}
__device__ __forceinline__ double wave_min_pack(double k) {
    k = fmin(k, dpp_f64<0x111>(k));
    k = fmin(k, dpp_f64<0x112>(k));
    k = fmin(k, dpp_f64<0x114>(k));
    k = fmin(k, dpp_f64<0x118>(k));
    k = fmin(k, dpp_f64<0x142>(k));
    k = fmin(k, dpp_f64<0x143>(k));
    return k;                          // lane 63 holds wave min
}
__device__ __forceinline__ uint64 bcast63_u64(double k) {
#if __has_builtin(__builtin_amdgcn_readlane)
    uint64 u = (uint64)__double_as_longlong(k);
    int lo = __builtin_amdgcn_readlane((int)(uint32)u, 63);
    int hi = __builtin_amdgcn_readlane((int)(uint32)(u >> 32), 63);
    return ((uint64)(uint32)hi << 32) | (uint32)lo;
#else
    return (uint64)__double_as_longlong(__shfl(k, 63));
#endif
}
#define FPS_WRITER_LANE 63
template <int CTRL>
__device__ __forceinline__ float dpp_mov_f32(float x) {
    int r = __builtin_amdgcn_update_dpp(__float_as_int(x), __float_as_int(x),
                                        CTRL, 0xf, 0xf, false);
    return __int_as_float(r);
}
__device__ __forceinline__ float wave_sum_f32(float v) {
    v += dpp_mov_f32<0x111>(v);
    v += dpp_mov_f32<0x112>(v);
    v += dpp_mov_f32<0x114>(v);
    v += dpp_mov_f32<0x118>(v);
    v += dpp_mov_f32<0x142>(v);
    v += dpp_mov_f32<0x143>(v);
    return v;                          // lane 63 holds wave sum
}
#define LIN_WRITER 63
#else
#define HAS_DPP 0
__device__ __forceinline__ double wave_max_pack(double k) {
#pragma unroll
    for (int m = 32; m >= 1; m >>= 1) k = fmax(k, __shfl_xor(k, m));
    return k;
}
__device__ __forceinline__ double wave_min_pack(double k) {
#pragma unroll
    for (int m = 32; m >= 1; m >>= 1) k = fmin(k, __shfl_xor(k, m));
    return k;
}
__device__ __forceinline__ uint64 bcast63_u64(double k) {
    return (uint64)__double_as_longlong(k);   // already in all lanes
}
#define FPS_WRITER_LANE 0
__device__ __forceinline__ float wave_sum_f32(float v) {
#pragma unroll
    for (int m = 32; m >= 1; m >>= 1) v += __shfl_xor(v, m);
    return v;
}
#define LIN_WRITER 0
#endif

// ------------------------------------------------------------------
// prep_all: blocks [0,512): transpose points [B,64,N]->[B,N,64] bf16;
//           blocks [512,1584): transpose conv weights + lin_w -> bf16
// ------------------------------------------------------------------
__global__ __launch_bounds__(256) void prep_all(const float* __restrict__ points,
                                                __hip_bfloat16* __restrict__ ptsT,
                                                const float* __restrict__ c1_w,
                                                const float* __restrict__ c2_w,
                                                const float* __restrict__ lin_w,
                                                float* __restrict__ w1t,
                                                float* __restrict__ w2t,
                                                __hip_bfloat16* __restrict__ linB) {
    int t = threadIdx.x;
    if (blockIdx.x < 512) {
        __shared__ float tile[64][65];
        int blk = blockIdx.x;
        int b = blk / (NN / 64);
        int n0 = (blk % (NN / 64)) * 64;
        for (int i = t; i < 4096; i += 256) {
            int d = i >> 6, n = i & 63;
            tile[d][n] = points[((size_t)b * DD + d) * NN + n0 + n];
        }
        __syncthreads();
        for (int i = t; i < 4096; i += 256) {
            int n = i >> 6, d = i & 63;
            ptsT[((size_t)b * NN + n0 + n) * DD + d] = __float2bfloat16(tile[d][n]);
        }
    } else {
        int i = (blockIdx.x - 512) * 256 + t;
        if (i < 4096) {
            int d = i >> 6, c = i & 63;
            w1t[d * 64 + c] = c1_w[c * 64 + d];
        }
        int j = i - 4096;
        if (j >= 0 && j < 8192) {
            int d = j >> 7, c = j & 127;
            w2t[d * 128 + c] = c2_w[c * 64 + d];
        }
        int l = i - 12288;
        if (l >= 0 && l < 262144) linB[l] = __float2bfloat16(lin_w[l]);
    }
}

// ------------------------------------------------------------------
// FPS: one block (512 thr) per batch; 8 pts/thread in registers;
// packed-f64 DPP argmax in the serial chain; one barrier/step;
// outputs via LDS hist + coalesced epilogue.
// ------------------------------------------------------------------
__global__ __launch_bounds__(512) void fps_kernel(const float* __restrict__ xyz,
                                                  float* __restrict__ new_xyz,
                                                  float* __restrict__ out0) {
    __shared__ float xs[NN], ys[NN], zs[NN];
    __shared__ int hist[SS];
    __shared__ __align__(16) double slots[2][8];
    int b = blockIdx.x, t = threadIdx.x;
    int wv = t >> 6, lane = t & 63;
    const float* base = xyz + (size_t)b * 3 * NN;
    float px[8], py[8], pz[8], dl[8];
    uint32 lidx[8];
#pragma unroll
    for (int i = 0; i < 8; i++) {
        int n = t + 512 * i;
        px[i] = base[n];
        py[i] = base[NN + n];
        pz[i] = base[2 * NN + n];
        xs[n] = px[i];
        ys[n] = py[i];
        zs[n] = pz[i];
        dl[i] = 1e10f;
        lidx[i] = (uint32)(NN - 1 - n);
    }
    if (t == 0) hist[0] = 0;
    __syncthreads();
    int far = 0;
    for (int step = 1; step < SS; step++) {
        int p = step & 1;
        float cx = xs[far], cy = ys[far], cz = zs[far];
        double kbest = 0.0;   // all real keys are >= +0.0
#pragma unroll
        for (int i = 0; i < 8; i++) {
            float dx = __fsub_rn(px[i], cx);
            float dy = __fsub_rn(py[i], cy);
            float dz = __fsub_rn(pz[i], cz);
            float d = __fadd_rn(__fadd_rn(__fmul_rn(dx, dx), __fmul_rn(dy, dy)),
                                __fmul_rn(dz, dz));
            float nd = fminf(dl[i], d);
            dl[i] = nd;
            uint64 kbits = ((uint64)__float_as_uint(nd) << 32) | lidx[i];
            kbest = fmax(kbest, __longlong_as_double((long long)kbits));
        }
        kbest = wave_max_pack(kbest);
        if (lane == FPS_WRITER_LANE) slots[p][wv] = kbest;
        __syncthreads();
        double s0 = slots[p][0], s1 = slots[p][1];
        double s2 = slots[p][2], s3 = slots[p][3];
        double s4 = slots[p][4], s5 = slots[p][5];
        double s6 = slots[p][6], s7 = slots[p][7];
        double m0 = fmax(s0, s1), m1 = fmax(s2, s3);
        double m2 = fmax(s4, s5), m3 = fmax(s6, s7);
        double bk = fmax(fmax(m0, m1), fmax(m2, m3));
        uint64 kb = (uint64)__double_as_longlong(bk);
        int bbx = (NN - 1) - (int)(uint32)(kb & 0xffffffffull);
        far = bbx;
        if (t == 0) hist[step] = bbx;
    }
    __syncthreads();
    // epilogue: coalesced output writes
    for (int s = t; s < SS; s += 512) {
        int idx = hist[s];
        float x = xs[idx], y = ys[idx], z = zs[idx];
        size_t q = (size_t)(b * SS + s);
        new_xyz[q * 3 + 0] = x;
        new_xyz[q * 3 + 1] = y;
        new_xyz[q * 3 + 2] = z;
        out0[(size_t)b * 3 * SS + 0 * SS + s] = x;
        out0[(size_t)b * 3 * SS + 1 * SS + s] = y;
        out0[(size_t)b * 3 * SS + 2 * SS + s] = z;
    }
}

// ------------------------------------------------------------------
// kNN: one wave per query; dists in registers, 64-bit exclusion mask.
// Inner scan is f32 compare/select (full-rate); only the cross-lane
// reduce uses the packed-f64 DPP min.
// ------------------------------------------------------------------
__global__ __launch_bounds__(256) void knn_wave(const float* __restrict__ xyz,
                                                const float* __restrict__ new_xyz,
                                                int* __restrict__ nidx,
                                                float* __restrict__ offs) {
    int wv = threadIdx.x >> 6, lane = threadIdx.x & 63;
    int q = blockIdx.x * 4 + wv;         // 0..8191
    int b = q >> 10;
    const float* base = xyz + (size_t)b * 3 * NN;
    float sx = new_xyz[(size_t)q * 3 + 0];
    float sy = new_xyz[(size_t)q * 3 + 1];
    float sz = new_xyz[(size_t)q * 3 + 2];
    float s2 = __fadd_rn(__fadd_rn(__fmul_rn(sx, sx), __fmul_rn(sy, sy)), __fmul_rn(sz, sz));
    float dl[64];
#pragma unroll
    for (int i = 0; i < 64; i++) {
        int n = i * 64 + lane;
        float x = base[n], y = base[NN + n], z = base[2 * NN + n];
        float d2 = __fadd_rn(__fadd_rn(__fmul_rn(x, x), __fmul_rn(y, y)), __fmul_rn(z, z));
        float dot = __fadd_rn(__fadd_rn(__fmul_rn(sx, x), __fmul_rn(sy, y)), __fmul_rn(sz, z));
        float v = __fmul_rn(-2.0f, dot);
        v = __fadd_rn(v, s2);
        v = __fadd_rn(v, d2);
        dl[i] = v;
    }
    const float MASKF = __uint_as_float(0x7F7FFFFFu);   // FLT_MAX
    unsigned long long excl = 0ull;
    for (int k = 0; k < KK; k++) {
        float best = MASKF;
        int bslot = 0;
#pragma unroll
        for (int i = 0; i < 64; i++) {
            bool ok = ((excl >> i) & 1ull) == 0ull;
            float v = ok ? dl[i] : MASKF;
            if (v < best) { best = v; bslot = i; }   // strict <: lowest slot kept
        }
        uint64 kbits = ((uint64)__float_as_uint(best) << 32) |
                       (uint32)(bslot * 64 + lane);
        double kb = wave_min_pack(__longlong_as_double((long long)kbits));
        uint64 r = bcast63_u64(kb);
        int bi = (int)(uint32)(r & 0xffffffffull);
        if ((bi & 63) == lane) excl |= (1ull << (bi >> 6));
        if (lane == 0) {
            nidx[(size_t)q * KK + k] = bi;
            size_t oo = ((size_t)q * KK + k) * 3;
            offs[oo + 0] = __fsub_rn(base[bi], sx);
            offs[oo + 1] = __fsub_rn(base[NN + bi], sy);
            offs[oo + 2] = __fsub_rn(base[2 * NN + bi], sz);
        }
    }
}

// ------------------------------------------------------------------
// staging: gather 32 neighbors x 64 dims (bf16 -> fp32 LDS), uint4 loads
// ------------------------------------------------------------------
__device__ __forceinline__ void stage_pts(const __hip_bfloat16* __restrict__ ptsT,
                                          const int* __restrict__ nidx,
                                          int q, int b, int t, float* pts) {
    int k = t >> 3, d8 = t & 7;
    int nn = nidx[(size_t)q * KK + k];
    uint4 u = ((const uint4*)ptsT)[((size_t)b * NN + nn) * 8 + d8];
    float4 lo, hi;
    lo.x = __uint_as_float(u.x << 16); lo.y = __uint_as_float(u.x & 0xffff0000u);
    lo.z = __uint_as_float(u.y << 16); lo.w = __uint_as_float(u.y & 0xffff0000u);
    hi.x = __uint_as_float(u.z << 16); hi.y = __uint_as_float(u.z & 0xffff0000u);
    hi.z = __uint_as_float(u.w << 16); hi.w = __uint_as_float(u.w & 0xffff0000u);
    *(float4*)&pts[k * 64 + d8 * 8] = lo;
    *(float4*)&pts[k * 64 + d8 * 8 + 4] = hi;
}

// ------------------------------------------------------------------
// pass A: conv1 stats + w0 stats (float4 LDS reads, slotted atomics)
// ------------------------------------------------------------------
__global__ __launch_bounds__(256) void pass_a(const __hip_bfloat16* __restrict__ ptsT,
                                              const int* __restrict__ nidx,
                                              const float* __restrict__ offs,
                                              const float* __restrict__ w1t,
                                              const float* __restrict__ c1_b,
                                              const float* __restrict__ w0_w,
                                              const float* __restrict__ w0_b,
                                              float* __restrict__ stats) {
    __shared__ __align__(16) float pts[2048];
    __shared__ float red1[256], red2[256];
    int blk = blockIdx.x, t = threadIdx.x;
    int b = blk >> 10;
    int slot = blk & (N_SLOTS - 1);
    stage_pts(ptsT, nidx, blk, b, t, pts);
    __syncthreads();
    int c = t & 63, kg = t >> 6;
    float bias = c1_b[c];
    float acc[8];
#pragma unroll
    for (int j = 0; j < 8; j++) acc[j] = bias;
    for (int d4 = 0; d4 < 16; d4++) {
        float w0 = w1t[(4 * d4 + 0) * 64 + c];
        float w1v = w1t[(4 * d4 + 1) * 64 + c];
        float w2v = w1t[(4 * d4 + 2) * 64 + c];
        float w3 = w1t[(4 * d4 + 3) * 64 + c];
#pragma unroll
        for (int j = 0; j < 8; j++) {
            const float4 p = *(const float4*)&pts[(kg + 4 * j) * 64 + 4 * d4];
            acc[j] = fmaf(p.x, w0, acc[j]);
            acc[j] = fmaf(p.y, w1v, acc[j]);
            acc[j] = fmaf(p.z, w2v, acc[j]);
            acc[j] = fmaf(p.w, w3, acc[j]);
        }
    }
    float s1 = 0.f, s2 = 0.f;
#pragma unroll
    for (int j = 0; j < 8; j++) { s1 += acc[j]; s2 += acc[j] * acc[j]; }
    red1[t] = s1;
    red2[t] = s2;
    __syncthreads();
    if (t < 64) {
        atomicAdd(&stats[slot * ST_STRIDE + ST_S1_C1 + t],
                  red1[t] + red1[t + 64] + red1[t + 128] + red1[t + 192]);
        atomicAdd(&stats[slot * ST_STRIDE + ST_S2_C1 + t],
                  red2[t] + red2[t + 64] + red2[t + 128] + red2[t + 192]);
    }
    // w0 stats
    int k0 = t >> 3, c0 = t & 7;
    size_t oo = ((size_t)blk * KK + k0) * 3;
    float h = w0_b[c0];
    h = fmaf(offs[oo + 0], w0_w[c0 * 3 + 0], h);
    h = fmaf(offs[oo + 1], w0_w[c0 * 3 + 1], h);
    h = fmaf(offs[oo + 2], w0_w[c0 * 3 + 2], h);
    __syncthreads();
    red1[t] = h;
    red2[t] = h * h;
    __syncthreads();
    if (t < 8) {
        float a = 0.f, q = 0.f;
        for (int j = t; j < 256; j += 8) { a += red1[j]; q += red2[j]; }
        atomicAdd(&stats[slot * ST_STRIDE + ST_S1_W0 + t], a);
        atomicAdd(&stats[slot * ST_STRIDE + ST_S2_W0 + t], q);
    }
}

// ------------------------------------------------------------------
// finalize BN(s) from slotted stats
// ------------------------------------------------------------------
__device__ __forceinline__ void fin_one(const float* stats, float* params,
                                        const float* g, const float* be,
                                        int s1o, int s2o, int ao, int co,
                                        int nch, float inv, int t) {
    if (t < nch) {
        float s1 = 0.f, s2 = 0.f;
        for (int s = 0; s < N_SLOTS; s++) {
            s1 += stats[s * ST_STRIDE + s1o + t];
            s2 += stats[s * ST_STRIDE + s2o + t];
        }
        float m = s1 * inv;
        float v = s2 * inv - m * m;
        float a = g[t] * rsqrtf(v + 1e-5f);
        params[ao + t] = a;
        params[co + t] = be[t] - m * a;
    }
}

__global__ void finalize_bn(const float* __restrict__ stats, float* __restrict__ params,
                            const float* __restrict__ g, const float* __restrict__ be,
                            int s1o, int s2o, int ao, int co, int nch, float inv) {
    fin_one(stats, params, g, be, s1o, s2o, ao, co, nch, inv, threadIdx.x);
}

__global__ void finalize_two(const float* __restrict__ stats, float* __restrict__ params,
                             const float* __restrict__ gA, const float* __restrict__ beA,
                             int s1A, int s2A, int aA, int cA, int nA, float invA,
                             const float* __restrict__ gB, const float* __restrict__ beB,
                             int s1B, int s2B, int aB, int cB, int nB, float invB) {
    if (blockIdx.x == 0)
        fin_one(stats, params, gA, beA, s1A, s2A, aA, cA, nA, invA, threadIdx.x);
    else
        fin_one(stats, params, gB, beB, s1B, s2B, aB, cB, nB, invB, threadIdx.x);
}

// ------------------------------------------------------------------
// pass B: conv1 recompute + bn1relu -> f1; conv2 stats; w1 stats
// ------------------------------------------------------------------
__global__ __launch_bounds__(256) void pass_b(const __hip_bfloat16* __restrict__ ptsT,
                                              const int* __restrict__ nidx,
                                              const float* __restrict__ offs,
                                              const float* __restrict__ w1t,
                                              const float* __restrict__ c1_b,
                                              const float* __restrict__ w2t,
                                              const float* __restrict__ c2_b,
                                              const float* __restrict__ w0_w,
                                              const float* __restrict__ w0_b,
                                              const float* __restrict__ w1_w,
                                              const float* __restrict__ w1_b,
                                              const float* __restrict__ params,
                                              float* __restrict__ stats) {
    __shared__ __align__(16) float pts[2048];
    __shared__ __align__(16) float f1[2048];
    __shared__ float red1[256], red2[256];
    int blk = blockIdx.x, t = threadIdx.x;
    int b = blk >> 10;
    int slot = blk & (N_SLOTS - 1);
    stage_pts(ptsT, nidx, blk, b, t, pts);
    __syncthreads();
    // conv1 + bn1 + relu
    {
        int c = t & 63, kg = t >> 6;
        float a1 = params[PA_A_C1 + c], cc1 = params[PA_C_C1 + c], bias = c1_b[c];
        float acc[8];
#pragma unroll
        for (int j = 0; j < 8; j++) acc[j] = bias;
        for (int d4 = 0; d4 < 16; d4++) {
            float w0 = w1t[(4 * d4 + 0) * 64 + c];
            float w1v = w1t[(4 * d4 + 1) * 64 + c];
            float w2v = w1t[(4 * d4 + 2) * 64 + c];
            float w3 = w1t[(4 * d4 + 3) * 64 + c];
#pragma unroll
            for (int j = 0; j < 8; j++) {
                const float4 p = *(const float4*)&pts[(kg + 4 * j) * 64 + 4 * d4];
                acc[j] = fmaf(p.x, w0, acc[j]);
                acc[j] = fmaf(p.y, w1v, acc[j]);
                acc[j] = fmaf(p.z, w2v, acc[j]);
                acc[j] = fmaf(p.w, w3, acc[j]);
            }
        }
#pragma unroll
        for (int j = 0; j < 8; j++)
            f1[(kg + 4 * j) * 64 + c] = fmaxf(fmaf(acc[j], a1, cc1), 0.f);
    }
    __syncthreads();
    // conv2 stats
    {
        int c = t & 127, kg = t >> 7;
        float bias = c2_b[c];
        float acc[16];
#pragma unroll
        for (int j = 0; j < 16; j++) acc[j] = bias;
        for (int d4 = 0; d4 < 16; d4++) {
            float w0 = w2t[(4 * d4 + 0) * 128 + c];
            float w1v = w2t[(4 * d4 + 1) * 128 + c];
            float w2v = w2t[(4 * d4 + 2) * 128 + c];
            float w3 = w2t[(4 * d4 + 3) * 128 + c];
#pragma unroll
            for (int j = 0; j < 16; j++) {
                const float4 p = *(const float4*)&f1[(kg + 2 * j) * 64 + 4 * d4];
                acc[j] = fmaf(p.x, w0, acc[j]);
                acc[j] = fmaf(p.y, w1v, acc[j]);
                acc[j] = fmaf(p.z, w2v, acc[j]);
                acc[j] = fmaf(p.w, w3, acc[j]);
            }
        }
        float s1 = 0.f, s2 = 0.f;
#pragma unroll
        for (int j = 0; j < 16; j++) { s1 += acc[j]; s2 += acc[j] * acc[j]; }
        red1[t] = s1;
        red2[t] = s2;
    }
    __syncthreads();
    if (t < 128) {
        atomicAdd(&stats[slot * ST_STRIDE + ST_S1_C2 + t], red1[t] + red1[t + 128]);
        atomicAdd(&stats[slot * ST_STRIDE + ST_S2_C2 + t], red2[t] + red2[t + 128]);
    }
    // w1 stats
    {
        int k0 = t >> 3, c0 = t & 7;
        size_t oo = ((size_t)blk * KK + k0) * 3;
        float o0 = offs[oo], o1 = offs[oo + 1], o2 = offs[oo + 2];
        float h0[8];
#pragma unroll
        for (int j = 0; j < 8; j++) {
            float hh = w0_b[j];
            hh = fmaf(o0, w0_w[j * 3 + 0], hh);
            hh = fmaf(o1, w0_w[j * 3 + 1], hh);
            hh = fmaf(o2, w0_w[j * 3 + 2], hh);
            h0[j] = fmaxf(fmaf(hh, params[PA_A_W0 + j], params[PA_C_W0 + j]), 0.f);
        }
        float h = w1_b[c0];
#pragma unroll
        for (int j = 0; j < 8; j++) h = fmaf(h0[j], w1_w[c0 * 8 + j], h);
        __syncthreads();
        red1[t] = h;
        red2[t] = h * h;
        __syncthreads();
        if (t < 8) {
            float a = 0.f, q = 0.f;
            for (int j = t; j < 256; j += 8) { a += red1[j]; q += red2[j]; }
            atomicAdd(&stats[slot * ST_STRIDE + ST_S1_W1 + t], a);
            atomicAdd(&stats[slot * ST_STRIDE + ST_S2_W1 + t], q);
        }
    }
}

// ------------------------------------------------------------------
// w2 stats: full weightnet chain per point
// ------------------------------------------------------------------
__global__ __launch_bounds__(256) void pass_w2(const float* __restrict__ offs,
                                               const float* __restrict__ w0_w,
                                               const float* __restrict__ w0_b,
                                               const float* __restrict__ w1_w,
                                               const float* __restrict__ w1_b,
                                               const float* __restrict__ w2_w,
                                               const float* __restrict__ w2_b,
                                               const float* __restrict__ params,
                                               float* __restrict__ stats) {
    int i = blockIdx.x * 256 + threadIdx.x;
    int slot = blockIdx.x & (N_SLOTS - 1);
    size_t oo = (size_t)i * 3;
    float o0 = offs[oo], o1 = offs[oo + 1], o2 = offs[oo + 2];
    float h0[8], h1[8];
#pragma unroll
    for (int j = 0; j < 8; j++) {
        float hh = w0_b[j];
        hh = fmaf(o0, w0_w[j * 3 + 0], hh);
        hh = fmaf(o1, w0_w[j * 3 + 1], hh);
        hh = fmaf(o2, w0_w[j * 3 + 2], hh);
        h0[j] = fmaxf(fmaf(hh, params[PA_A_W0 + j], params[PA_C_W0 + j]), 0.f);
    }
#pragma unroll
    for (int j = 0; j < 8; j++) {
        float hh = w1_b[j];
#pragma unroll
        for (int q = 0; q < 8; q++) hh = fmaf(h0[q], w1_w[j * 8 + q], hh);
        h1[j] = fmaxf(fmaf(hh, params[PA_A_W1 + j], params[PA_C_W1 + j]), 0.f);
    }
#pragma unroll
    for (int c = 0; c < 16; c++) {
        float h = w2_b[c];
#pragma unroll
        for (int q = 0; q < 8; q++) h = fmaf(h1[q], w2_w[c * 8 + q], h);
        float v = wave_sum_f32(h);
        float s = wave_sum_f32(h * h);
        if ((threadIdx.x & 63) == LIN_WRITER) {
            atomicAdd(&stats[slot * ST_STRIDE + ST_S1_W2 + c], v);
            atomicAdd(&stats[slot * ST_STRIDE + ST_S2_W2 + c], s);
        }
    }
}

// ------------------------------------------------------------------
// fused tail (NQ=1, R8 structure — best measured):
// conv1->conv2->weightnet->einsum->linear + y stats
// ------------------------------------------------------------------
__global__ __launch_bounds__(256) void fused_tail(
        const __hip_bfloat16* __restrict__ ptsT, const int* __restrict__ nidx,
        const float* __restrict__ offs,
        const float* __restrict__ w1t, const float* __restrict__ c1_b,
        const float* __restrict__ w2t, const float* __restrict__ c2_b,
        const float* __restrict__ w0_w, const float* __restrict__ w0_b,
        const float* __restrict__ w1_w, const float* __restrict__ w1_b,
        const float* __restrict__ w2_w, const float* __restrict__ w2_b,
        const __hip_bfloat16* __restrict__ linB, const float* __restrict__ lin_b,
        const float* __restrict__ params, float* __restrict__ stats,
        float* __restrict__ ypre) {
    __shared__ __align__(16) float sm[8704];
    float* pts   = sm;            // [0,2048)  later reused as feats
    float* f1    = sm + 2048;     // [2048,4096)
    float* f2    = sm + 4096;     // [4096,8192)
    float* wg    = sm + 8192;     // [8192,8704)
    int blk = blockIdx.x, t = threadIdx.x;
    int b = blk >> 10;
    int slot = blk & (N_SLOTS - 1);
    stage_pts(ptsT, nidx, blk, b, t, pts);
    // weightnet -> wg (independent of pts)
    for (int idx = t; idx < KK * 16; idx += 256) {
        int k = idx >> 4, cw = idx & 15;
        size_t oo = ((size_t)blk * KK + k) * 3;
        float o0 = offs[oo], o1 = offs[oo + 1], o2 = offs[oo + 2];
        float h0[8], h1[8];
#pragma unroll
        for (int j = 0; j < 8; j++) {
            float hh = w0_b[j];
            hh = fmaf(o0, w0_w[j * 3 + 0], hh);
            hh = fmaf(o1, w0_w[j * 3 + 1], hh);
            hh = fmaf(o2, w0_w[j * 3 + 2], hh);
            h0[j] = fmaxf(fmaf(hh, params[PA_A_W0 + j], params[PA_C_W0 + j]), 0.f);
        }
#pragma unroll
        for (int j = 0; j < 8; j++) {
            float hh = w1_b[j];
#pragma unroll
            for (int q = 0; q < 8; q++) hh = fmaf(h0[q], w1_w[j * 8 + q], hh);
            h1[j] = fmaxf(fmaf(hh, params[PA_A_W1 + j], params[PA_C_W1 + j]), 0.f);
        }
        float h = w2_b[cw];
#pragma unroll
        for (int q = 0; q < 8; q++) h = fmaf(h1[q], w2_w[cw * 8 + q], h);
        wg[idx] = fmaxf(fmaf(h, params[PA_A_W2 + cw], params[PA_C_W2 + cw]), 0.f);
    }
    __syncthreads();
    // conv1 + bn1 relu -> f1
    {
        int c = t & 63, kg = t >> 6;
        float a1 = params[PA_A_C1 + c], cc1 = params[PA_C_C1 + c], bias = c1_b[c];
        float acc[8];
#pragma unroll
        for (int j = 0; j < 8; j++) acc[j] = bias;
        for (int d4 = 0; d4 < 16; d4++) {
            float w0 = w1t[(4 * d4 + 0) * 64 + c];
            float w1v = w1t[(4 * d4 + 1) * 64 + c];
            float w2v = w1t[(4 * d4 + 2) * 64 + c];
            float w3 = w1t[(4 * d4 + 3) * 64 + c];
#pragma unroll
            for (int j = 0; j < 8; j++) {
                const float4 p = *(const float4*)&pts[(kg + 4 * j) * 64 + 4 * d4];
                acc[j] = fmaf(p.x, w0, acc[j]);
                acc[j] = fmaf(p.y, w1v, acc[j]);
                acc[j] = fmaf(p.z, w2v, acc[j]);
                acc[j] = fmaf(p.w, w3, acc[j]);
            }
        }
#pragma unroll
        for (int j = 0; j < 8; j++)
            f1[(kg + 4 * j) * 64 + c] = fmaxf(fmaf(acc[j], a1, cc1), 0.f);
    }
    __syncthreads();
    // conv2 + bn2 relu -> f2
    {
        int c = t & 127, kg = t >> 7;
        float a2 = params[PA_A_C2 + c], cc2 = params[PA_C_C2 + c], bias = c2_b[c];
        float acc[16];
#pragma unroll
        for (int j = 0; j < 16; j++) acc[j] = bias;
        for (int d4 = 0; d4 < 16; d4++) {
            float w0 = w2t[(4 * d4 + 0) * 128 + c];
            float w1v = w2t[(4 * d4 + 1) * 128 + c];
            float w2v = w2t[(4 * d4 + 2) * 128 + c];
            float w3 = w2t[(4 * d4 + 3) * 128 + c];
#pragma unroll
            for (int j = 0; j < 16; j++) {
                const float4 p = *(const float4*)&f1[(kg + 2 * j) * 64 + 4 * d4];
                acc[j] = fmaf(p.x, w0, acc[j]);
                acc[j] = fmaf(p.y, w1v, acc[j]);
                acc[j] = fmaf(p.z, w2v, acc[j]);
                acc[j] = fmaf(p.w, w3, acc[j]);
            }
        }
#pragma unroll
        for (int j = 0; j < 16; j++)
            f2[(kg + 2 * j) * 128 + c] = fmaxf(fmaf(acc[j], a2, cc2), 0.f);
    }
    __syncthreads();
    // einsum -> feats (aliases pts): thread owns cc = t&127, w-half = t>>7
    {
        int cc = t & 127, wh = t >> 7;
        float acc[8];
#pragma unroll
        for (int i = 0; i < 8; i++) acc[i] = 0.f;
        for (int k = 0; k < KK; k++) {
            float fv = f2[k * 128 + cc];
            const float4 wa = *(const float4*)&wg[k * 16 + 8 * wh];
            const float4 wb = *(const float4*)&wg[k * 16 + 8 * wh + 4];
            acc[0] = fmaf(fv, wa.x, acc[0]);
            acc[1] = fmaf(fv, wa.y, acc[1]);
            acc[2] = fmaf(fv, wa.z, acc[2]);
            acc[3] = fmaf(fv, wa.w, acc[3]);
            acc[4] = fmaf(fv, wb.x, acc[4]);
            acc[5] = fmaf(fv, wb.y, acc[5]);
            acc[6] = fmaf(fv, wb.z, acc[6]);
            acc[7] = fmaf(fv, wb.w, acc[7]);
        }
        *(float4*)&pts[cc * 16 + 8 * wh]     = *(float4*)&acc[0];
        *(float4*)&pts[cc * 16 + 8 * wh + 4] = *(float4*)&acc[4];
    }
    __syncthreads();
    float* feats = pts;
    // linear 2048 -> 128: feats hoisted to registers, DPP wave-sum
    {
        int wv = t >> 6, lane = t & 63;
        float4 fv[8];
#pragma unroll
        for (int j0 = 0; j0 < 8; j0++)
            fv[j0] = *(const float4*)&feats[(j0 * 64 + lane) * 4];
        for (int oi = 0; oi < 32; oi++) {
            int o = wv * 32 + oi;
            const uint2* lw = (const uint2*)(linB + (size_t)o * 2048);
            float acc = 0.f;
#pragma unroll
            for (int j0 = 0; j0 < 8; j0++) {
                uint2 u = lw[j0 * 64 + lane];
                acc = fmaf(fv[j0].x, __uint_as_float(u.x << 16), acc);
                acc = fmaf(fv[j0].y, __uint_as_float(u.x & 0xffff0000u), acc);
                acc = fmaf(fv[j0].z, __uint_as_float(u.y << 16), acc);
                acc = fmaf(fv[j0].w, __uint_as_float(u.y & 0xffff0000u), acc);
            }
            acc = wave_sum_f32(acc);
            if (lane == LIN_WRITER) {
                float y = acc + lin_b[o];
                ypre[(size_t)blk * 128 + o] = y;
                atomicAdd(&stats[slot * ST_STRIDE + ST_S1_Y + o], y);
                atomicAdd(&stats[slot * ST_STRIDE + ST_S2_Y + o], y * y);
            }
        }
    }
}

// ------------------------------------------------------------------
// final BN + relu + tiled transpose write to out1 [B,128,S].
// Y-BN finalize folded in: each block computes A/C for all 128
// channels from slotted stats (16K L2 reads/block, ~1us aggregate) —
// saves the separate finalize launch.
// ------------------------------------------------------------------
__global__ __launch_bounds__(256) void bn_y(const float* __restrict__ ypre,
                                            const float* __restrict__ stats,
                                            const float* __restrict__ lg,
                                            const float* __restrict__ lb,
                                            float* __restrict__ out1) {
    __shared__ float tile[64 * 133];
    __shared__ float pa[128], pc[128];
    int blk = blockIdx.x;
    int b = blk >> 4;
    int s0 = (blk & 15) * 64;
    int t = threadIdx.x;
    if (t < 128) {
        float s1 = 0.f, s2 = 0.f;
        for (int s = 0; s < N_SLOTS; s++) {
            s1 += stats[s * ST_STRIDE + ST_S1_Y + t];
            s2 += stats[s * ST_STRIDE + ST_S2_Y + t];
        }
        const float inv = 1.f / (float)BS;
        float m = s1 * inv;
        float v = s2 * inv - m * m;
        float a = lg[t] * rsqrtf(v + 1e-5f);
        pa[t] = a;
        pc[t] = lb[t] - m * a;
    }
#pragma unroll
    for (int i = 0; i < 32; i++) {
        int idx = i * 256 + t;
        int s = idx >> 7, c = idx & 127;
        tile[s * 133 + c] = ypre[(((size_t)b << 10) + s0 + s) * 128 + c];
    }
    __syncthreads();
#pragma unroll
    for (int i = 0; i < 32; i++) {
        int idx = i * 256 + t;
        int c = idx >> 6, s = idx & 63;
        float v = tile[s * 133 + c];
        out1[((size_t)b * 128 + c) * 1024 + s0 + s] =
            fmaxf(fmaf(v, pa[c], pc[c]), 0.f);
    }
}

// ------------------------------------------------------------------
extern "C" void kernel_launch(void* const* d_in, const int* in_sizes, int n_in,
                              void* d_out, int out_size, void* d_ws, size_t ws_size,
                              hipStream_t stream) {
    const float* xyz    = (const float*)d_in[0];
    const float* points = (const float*)d_in[1];
    const float* c1_w = (const float*)d_in[2];
    const float* c1_b = (const float*)d_in[3];
    const float* g1   = (const float*)d_in[4];
    const float* b1   = (const float*)d_in[5];
    const float* c2_w = (const float*)d_in[6];
    const float* c2_b = (const float*)d_in[7];
    const float* g2   = (const float*)d_in[8];
    const float* b2   = (const float*)d_in[9];
    const float* w0_w = (const float*)d_in[10];
    const float* w0_b = (const float*)d_in[11];
    const float* w0_g = (const float*)d_in[12];
    const float* w0_be= (const float*)d_in[13];
    const float* w1_w = (const float*)d_in[14];
    const float* w1_b = (const float*)d_in[15];
    const float* w1_g = (const float*)d_in[16];
    const float* w1_be= (const float*)d_in[17];
    const float* w2_w = (const float*)d_in[18];
    const float* w2_b = (const float*)d_in[19];
    const float* w2_g = (const float*)d_in[20];
    const float* w2_be= (const float*)d_in[21];
    const float* lin_w= (const float*)d_in[22];
    const float* lin_b= (const float*)d_in[23];
    const float* lg   = (const float*)d_in[24];
    const float* lb   = (const float*)d_in[25];

    float* out0 = (float*)d_out;
    float* out1 = out0 + (size_t)BB * 3 * SS;

    char* wsb = (char*)d_ws;
    int*   nidx    = (int*)(wsb + 0);                         // 1,048,576
    float* offs    = (float*)(wsb + 1048576);                 // 3,145,728
    float* new_xyz = (float*)(wsb + 4194304);                 // 98,304
    float* ypre    = (float*)(wsb + 4292608);                 // 4,194,304
    __hip_bfloat16* ptsT = (__hip_bfloat16*)(wsb + 8486912);  // 4,194,304
    float* w1t     = (float*)(wsb + 12681216);                // 16,384
    float* w2t     = (float*)(wsb + 12697600);                // 32,768
    __hip_bfloat16* linB = (__hip_bfloat16*)(wsb + 12730368); // 524,288
    float* stats   = (float*)(wsb + 13254656);                // 180,224
    float* params  = (float*)(wsb + 13434880);                // 2,816

    hipMemsetAsync(stats, 0, N_SLOTS * ST_STRIDE * sizeof(float), stream);

    prep_all<<<1584, 256, 0, stream>>>(points, ptsT, c1_w, c2_w, lin_w, w1t, w2t, linB);
    fps_kernel<<<BB, 512, 0, stream>>>(xyz, new_xyz, out0);
    knn_wave<<<BS / 4, 256, 0, stream>>>(xyz, new_xyz, nidx, offs);

    pass_a<<<BS, 256, 0, stream>>>(ptsT, nidx, offs, w1t, c1_b, w0_w, w0_b, stats);
    finalize_two<<<2, 128, 0, stream>>>(stats, params,
                                        g1, b1, ST_S1_C1, ST_S2_C1, PA_A_C1, PA_C_C1, 64, 1.f / BSK,
                                        w0_g, w0_be, ST_S1_W0, ST_S2_W0, PA_A_W0, PA_C_W0, 8, 1.f / BSK);

    pass_b<<<BS, 256, 0, stream>>>(ptsT, nidx, offs, w1t, c1_b, w2t, c2_b,
                                   w0_w, w0_b, w1_w, w1_b, params, stats);
    finalize_two<<<2, 128, 0, stream>>>(stats, params,
                                        g2, b2, ST_S1_C2, ST_S2_C2, PA_A_C2, PA_C_C2, 128, 1.f / BSK,
                                        w1_g, w1_be, ST_S1_W1, ST_S2_W1, PA_A_W1, PA_C_W1, 8, 1.f / BSK);

    pass_w2<<<BSK / 256, 256, 0, stream>>>(offs, w0_w, w0_b, w1_w, w1_b, w2_w, w2_b,
                                           params, stats);
    finalize_bn<<<1, 128, 0, stream>>>(stats, params, w2_g, w2_be,
                                       ST_S1_W2, ST_S2_W2, PA_A_W2, PA_C_W2, 16, 1.f / BSK);

    fused_tail<<<BS, 256, 0, stream>>>(ptsT, nidx, offs, w1t, c1_b, w2t, c2_b,
                                       w0_w, w0_b, w1_w, w1_b, w2_w, w2_b,
                                       linB, lin_b, params, stats, ypre);

    bn_y<<<BB * 16, 256, 0, stream>>>(ypre, stats, lg, lb, out1);
}